// Round 5
// baseline (764.147 us; speedup 1.0000x reference)
//
#include <hip/hip_runtime.h>

// RelativeLearnableAttention — MI355X (round 5)
// B=4 N=2048 DIM=256 H=8 D=32, scale = 1/16.
// Contract (established empirically R1–R4): inputs f32, mask int32,
// d_out = FLOAT32 (out [4,2048,256] ++ attn [4,8,2048,2048]).
// Internals: bf16 MFMA pipeline (kprep converts once); final stores f32.

typedef short bf16x8 __attribute__((ext_vector_type(8)));
typedef float f32x4 __attribute__((ext_vector_type(4)));

#define SCALE 0.0625f

static __device__ __forceinline__ unsigned short f2b(float f) {
    union { float f; unsigned int u; } x; x.f = f;
    unsigned int r = x.u + 0x7fffu + ((x.u >> 16) & 1u);   // RNE
    return (unsigned short)(r >> 16);
}

// ---------------------------------------------------------------------------
// Prep: f32->bf16 of w, r; transpose+convert Wqkv/Wr/Wout; mask -> mw[b][i]
// (left-pad True). 12 MB traffic.
__global__ __launch_bounds__(256) void kprep(
    const float* __restrict__ w, const float* __restrict__ r,
    const float* __restrict__ Wqkv, const float* __restrict__ Wr,
    const float* __restrict__ Wout, const int* __restrict__ amask,
    unsigned short* __restrict__ wb, unsigned short* __restrict__ rb,
    unsigned short* __restrict__ WqkvT, unsigned short* __restrict__ WrT,
    unsigned short* __restrict__ WoutT, int* __restrict__ mw)
{
    int o = blockIdx.x * 256 + threadIdx.x;
    if (o < 2097152) { wb[o] = f2b(w[o]); return; }
    o -= 2097152;
    if (o < 524288) { rb[o] = f2b(r[o]); return; }
    o -= 524288;
    if (o < 196608) { int n = o >> 8, k = o & 255; WqkvT[o] = f2b(Wqkv[k * 768 + n]); return; }
    o -= 196608;
    if (o < 65536) { int n = o >> 8, k = o & 255; WrT[o] = f2b(Wr[k * 256 + n]); return; }
    o -= 65536;
    if (o < 65536) { int n = o >> 8, k = o & 255; WoutT[o] = f2b(Wout[k * 256 + n]); return; }
    o -= 65536;
    {   // o in [0, 8192)
        const int b = o >> 11, i = o & 2047;
        mw[o] = (i == 0) ? 1 : (amask[b * 2047 + i - 1] != 0);
    }
}

// ---------------------------------------------------------------------------
// QKV GEMM: [8192x256] @ [256x768]; epilogue splits q/k/v, adds f32 biases to q,
// writes q1=(q+r_w_bias), q2=(q+r_r_bias), k as [bh][n][32], v transposed [bh][32][n].
__global__ __launch_bounds__(256) void kqkv(
    const unsigned short* __restrict__ w,      // [8192][256] bf16
    const unsigned short* __restrict__ WqkvT,  // [768][256] bf16
    const float* __restrict__ rwb,             // [256] f32 (h*32+d)
    const float* __restrict__ rrb,             // [256] f32
    unsigned short* __restrict__ q1w,          // [32][2048][32]
    unsigned short* __restrict__ q2w,
    unsigned short* __restrict__ kw,           // [32][2048][32]
    unsigned short* __restrict__ vTw)          // [32][32][2048]
{
    const int m0 = blockIdx.x * 64;
    const int n0 = blockIdx.y * 64;
    const int tid = threadIdx.x;
    const int wid = tid >> 6, lane = tid & 63;
    const int l16 = lane & 15, quad = lane >> 4;

    f32x4 acc[4] = {};
    const unsigned short* arow = w + (m0 + wid * 16 + l16) * 256 + quad * 8;
    for (int kc = 0; kc < 8; ++kc) {
        bf16x8 aF = *(const bf16x8*)(arow + kc * 32);
#pragma unroll
        for (int t = 0; t < 4; ++t) {
            bf16x8 bF = *(const bf16x8*)(WqkvT + (n0 + t * 16 + l16) * 256 + kc * 32 + quad * 8);
            acc[t] = __builtin_amdgcn_mfma_f32_16x16x32_bf16(aF, bF, acc[t], 0, 0, 0);
        }
    }
#pragma unroll
    for (int t = 0; t < 4; ++t) {
        const int cbase = n0 + t * 16;        // wave-uniform; never straddles a section/head
        const int sect = cbase >> 8;          // 0=q 1=k 2=v
        const int h = (cbase & 255) >> 5;
        const int d = (cbase & 31) + l16;
        const int m = m0 + wid * 16 + quad * 4;
        const int b = m >> 11;
        const int n = m & 2047;
        const int bh = b * 8 + h;
        if (sect == 0) {
            const float bw = rwb[h * 32 + d];
            const float br = rrb[h * 32 + d];
#pragma unroll
            for (int rr = 0; rr < 4; ++rr) {
                int idx = (bh * 2048 + n + rr) * 32 + d;
                q1w[idx] = f2b(acc[t][rr] + bw);
                q2w[idx] = f2b(acc[t][rr] + br);
            }
        } else if (sect == 1) {
#pragma unroll
            for (int rr = 0; rr < 4; ++rr)
                kw[(bh * 2048 + n + rr) * 32 + d] = f2b(acc[t][rr]);
        } else {
            ushort4 u;
            u.x = f2b(acc[t][0]); u.y = f2b(acc[t][1]);
            u.z = f2b(acc[t][2]); u.w = f2b(acc[t][3]);
            *(ushort4*)(vTw + (bh * 32 + d) * 2048 + n) = u;   // n is 4-aligned
        }
    }
}

// ---------------------------------------------------------------------------
// [Mx256] @ [256x256] bf16 GEMM, bf16 output (internal: r@Wr).
__global__ __launch_bounds__(256) void kgemm256b(
    const unsigned short* __restrict__ A, const unsigned short* __restrict__ BT,
    unsigned short* __restrict__ C)
{
    const int m0 = blockIdx.x * 64;
    const int n0 = blockIdx.y * 64;
    const int tid = threadIdx.x;
    const int wid = tid >> 6, lane = tid & 63;
    const int l16 = lane & 15, quad = lane >> 4;

    f32x4 acc[4] = {};
    const unsigned short* arow = A + (m0 + wid * 16 + l16) * 256 + quad * 8;
    for (int kc = 0; kc < 8; ++kc) {
        bf16x8 aF = *(const bf16x8*)(arow + kc * 32);
#pragma unroll
        for (int t = 0; t < 4; ++t) {
            bf16x8 bF = *(const bf16x8*)(BT + (n0 + t * 16 + l16) * 256 + kc * 32 + quad * 8);
            acc[t] = __builtin_amdgcn_mfma_f32_16x16x32_bf16(aF, bF, acc[t], 0, 0, 0);
        }
    }
#pragma unroll
    for (int t = 0; t < 4; ++t) {
        const int c = n0 + t * 16 + l16;
        const int m = m0 + wid * 16 + quad * 4;
#pragma unroll
        for (int rr = 0; rr < 4; ++rr)
            C[(m + rr) * 256 + c] = f2b(acc[t][rr]);
    }
}

// ---------------------------------------------------------------------------
// [Mx256] @ [256x256] bf16 GEMM, FLOAT32 output (final: ctx@Wout -> d_out).
__global__ __launch_bounds__(256) void kgemm256f(
    const unsigned short* __restrict__ A, const unsigned short* __restrict__ BT,
    float* __restrict__ C)
{
    const int m0 = blockIdx.x * 64;
    const int n0 = blockIdx.y * 64;
    const int tid = threadIdx.x;
    const int wid = tid >> 6, lane = tid & 63;
    const int l16 = lane & 15, quad = lane >> 4;

    f32x4 acc[4] = {};
    const unsigned short* arow = A + (m0 + wid * 16 + l16) * 256 + quad * 8;
    for (int kc = 0; kc < 8; ++kc) {
        bf16x8 aF = *(const bf16x8*)(arow + kc * 32);
#pragma unroll
        for (int t = 0; t < 4; ++t) {
            bf16x8 bF = *(const bf16x8*)(BT + (n0 + t * 16 + l16) * 256 + kc * 32 + quad * 8);
            acc[t] = __builtin_amdgcn_mfma_f32_16x16x32_bf16(aF, bF, acc[t], 0, 0, 0);
        }
    }
#pragma unroll
    for (int t = 0; t < 4; ++t) {
        const int c = n0 + t * 16 + l16;
        const int m = m0 + wid * 16 + quad * 4;
#pragma unroll
        for (int rr = 0; rr < 4; ++rr)
            C[(m + rr) * 256 + c] = acc[t][rr];
    }
}

// ---------------------------------------------------------------------------
// Fused attention. Block = 4 independent waves; wave owns 16 rows, sweeps all 2048 j.
// m=0 softmax (shift-invariant; |s*scale| <~ 2.5 -> no overflow).
// Fully-masked rows: p=1 forall j -> attn=1/2048 (matches reference).
// Pass A: scores -> p -> l += p, PV accumulate (p through LDS for C->A layout).
// Pass B: recompute scores, store attn = p/l DIRECTLY as f32 (C-layout, 64B segments).
__global__ __launch_bounds__(256) void kattn(
    const unsigned short* __restrict__ q1w,  // [32][2048][32]
    const unsigned short* __restrict__ q2w,
    const unsigned short* __restrict__ kw,   // [32][2048][32]
    const unsigned short* __restrict__ vTw,  // [32][32][2048]
    const unsigned short* __restrict__ rr,   // flat [8][2048][32] (literal reshape of r@Wr)
    const int* __restrict__ mw,              // [4][2048] (i=0 true)
    float* __restrict__ attn,                // [32][2048][2048] f32
    unsigned short* __restrict__ ctx)        // [4][2048][256] bf16 (b, i, h*32+d)
{
    __shared__ __align__(16) unsigned short pbuf[4][16][72];  // pass A repack

    const int blk = blockIdx.x;      // 1024 = 32 bh * 32 i-tiles
    const int it = blk & 31;
    const int bh = blk >> 5;
    const int b = bh >> 3, h = bh & 7;
    const int tid = threadIdx.x;
    const int wid = tid >> 6, lane = tid & 63;
    const int l16 = lane & 15, quad = lane >> 4;
    const int i0 = it * 64 + wid * 16;

    const bf16x8 a1 = *(const bf16x8*)(q1w + (bh * 2048 + i0 + l16) * 32 + quad * 8);
    const bf16x8 a2 = *(const bf16x8*)(q2w + (bh * 2048 + i0 + l16) * 32 + quad * 8);

    const int* mwb = mw + b * 2048;
    float mi[4];
#pragma unroll
    for (int r = 0; r < 4; ++r)
        mi[r] = mwb[i0 + quad * 4 + r] ? 1.f : 0.f;

    const unsigned short* kbase = kw + bh * 2048 * 32;
    const unsigned short* rbase = rr + h * 65536;
    const unsigned short* vbase = vTw + bh * 32 * 2048;

    float lsum[4] = {0.f, 0.f, 0.f, 0.f};
    f32x4 oacc[2] = {};
    unsigned short (*pb)[72] = pbuf[wid];

    // ---- pass A: l accumulation + PV ----
    for (int jt = 0; jt < 32; ++jt) {
        const int j0 = jt * 64;
        f32x4 s[4];
#pragma unroll
        for (int t = 0; t < 4; ++t) {
            bf16x8 bK = *(const bf16x8*)(kbase + (j0 + t * 16 + l16) * 32 + quad * 8);
            bf16x8 bR = *(const bf16x8*)(rbase + (j0 + t * 16 + l16) * 32 + quad * 8);
            f32x4 z = {};
            z = __builtin_amdgcn_mfma_f32_16x16x32_bf16(a1, bK, z, 0, 0, 0);
            s[t] = __builtin_amdgcn_mfma_f32_16x16x32_bf16(a2, bR, z, 0, 0, 0);
        }
#pragma unroll
        for (int t = 0; t < 4; ++t) {
            const float mj = mwb[j0 + t * 16 + l16] ? 1.f : 0.f;
#pragma unroll
            for (int r = 0; r < 4; ++r) {
                float p = (mi[r] == 0.f) ? 1.f : ((mj != 0.f) ? __expf(s[t][r] * SCALE) : 0.f);
                lsum[r] += p;
                pb[quad * 4 + r][t * 16 + l16] = f2b(p);
            }
        }
        asm volatile("s_waitcnt lgkmcnt(0)" ::: "memory");   // in-wave LDS visibility
#pragma unroll
        for (int kc = 0; kc < 2; ++kc) {
            bf16x8 pA = *(const bf16x8*)(&pb[l16][kc * 32 + quad * 8]);
#pragma unroll
            for (int dt = 0; dt < 2; ++dt) {
                bf16x8 bV = *(const bf16x8*)(vbase + (dt * 16 + l16) * 2048 + j0 + kc * 32 + quad * 8);
                oacc[dt] = __builtin_amdgcn_mfma_f32_16x16x32_bf16(pA, bV, oacc[dt], 0, 0, 0);
            }
        }
        asm volatile("s_waitcnt lgkmcnt(0)" ::: "memory");   // WAR before next overwrite
    }

    // ---- finalize l: sum across the 16 lanes of each quad-group ----
    float invl[4];
#pragma unroll
    for (int r = 0; r < 4; ++r) {
        float v = lsum[r];
        v += __shfl_xor(v, 1);
        v += __shfl_xor(v, 2);
        v += __shfl_xor(v, 4);
        v += __shfl_xor(v, 8);
        invl[r] = 1.0f / v;
    }

    // ---- pass B: recompute scores, store normalized attn as f32 ----
    float* abase = attn + (bh * 2048 + i0) * 2048;
    for (int jt = 0; jt < 32; ++jt) {
        const int j0 = jt * 64;
        f32x4 s[4];
#pragma unroll
        for (int t = 0; t < 4; ++t) {
            bf16x8 bK = *(const bf16x8*)(kbase + (j0 + t * 16 + l16) * 32 + quad * 8);
            bf16x8 bR = *(const bf16x8*)(rbase + (j0 + t * 16 + l16) * 32 + quad * 8);
            f32x4 z = {};
            z = __builtin_amdgcn_mfma_f32_16x16x32_bf16(a1, bK, z, 0, 0, 0);
            s[t] = __builtin_amdgcn_mfma_f32_16x16x32_bf16(a2, bR, z, 0, 0, 0);
        }
#pragma unroll
        for (int t = 0; t < 4; ++t) {
            const float mj = mwb[j0 + t * 16 + l16] ? 1.f : 0.f;
            float* dst = abase + j0 + t * 16 + l16 + (quad * 4) * 2048;
#pragma unroll
            for (int r = 0; r < 4; ++r) {
                float p = (mi[r] == 0.f) ? 1.f : ((mj != 0.f) ? __expf(s[t][r] * SCALE) : 0.f);
                dst[r * 2048] = p * invl[r];
            }
        }
    }

    // ---- epilogue: O / l -> ctx (bf16 internal) ----
#pragma unroll
    for (int dt = 0; dt < 2; ++dt)
#pragma unroll
        for (int r = 0; r < 4; ++r) {
            float o = oacc[dt][r] * invl[r];
            ctx[(b * 2048 + i0 + quad * 4 + r) * 256 + h * 32 + dt * 16 + l16] = f2b(o);
        }
}

// ---------------------------------------------------------------------------
extern "C" void kernel_launch(void* const* d_in, const int* in_sizes, int n_in,
                              void* d_out, int out_size, void* d_ws, size_t ws_size,
                              hipStream_t stream) {
    const float* w    = (const float*)d_in[0];  // [4][2048][256]
    const float* r    = (const float*)d_in[1];  // [2048][256]
    const int*   am   = (const int*)d_in[2];    // [4][2047]
    const float* Wqkv = (const float*)d_in[3];  // [256][768]
    const float* Wr   = (const float*)d_in[4];  // [256][256]
    const float* Wout = (const float*)d_in[5];  // [256][256]
    const float* rwb  = (const float*)d_in[6];  // [8][1][32]
    const float* rrb  = (const float*)d_in[7];  // [8][1][32]

    float* out  = (float*)d_out;                // [4][2048][256] f32
    float* attn = out + 4 * 2048 * 256;         // [4][8][2048][2048] f32

    unsigned short* ws    = (unsigned short*)d_ws;          // ~27 MB bf16 scratch
    unsigned short* wb    = ws;                             // 2,097,152
    unsigned short* rb    = wb + 2097152;                   // 524,288
    unsigned short* q1w   = rb + 524288;                    // 2,097,152
    unsigned short* q2w   = q1w + 2097152;
    unsigned short* kw    = q2w + 2097152;
    unsigned short* vTw   = kw + 2097152;
    unsigned short* rrw   = vTw + 2097152;                  // 524,288
    unsigned short* ctx   = rrw + 524288;                   // 2,097,152
    unsigned short* WqkvT = ctx + 2097152;                  // 196,608
    unsigned short* WrT   = WqkvT + 196608;                 // 65,536
    unsigned short* WoutT = WrT + 65536;                    // 65,536
    int*            mwp   = (int*)(WoutT + 65536);          // 8,192 ints

    kprep    <<<dim3(11558),   dim3(256), 0, stream>>>(w, r, Wqkv, Wr, Wout, am,
                                                       wb, rb, WqkvT, WrT, WoutT, mwp);
    kqkv     <<<dim3(128, 12), dim3(256), 0, stream>>>(wb, WqkvT, rwb, rrb, q1w, q2w, kw, vTw);
    kgemm256b<<<dim3(32, 4),   dim3(256), 0, stream>>>(rb, WrT, rrw);
    kattn    <<<dim3(1024),    dim3(256), 0, stream>>>(q1w, q2w, kw, vTw, rrw, mwp, attn, ctx);
    kgemm256f<<<dim3(128, 4),  dim3(256), 0, stream>>>(ctx, WoutT, out);
}